// Round 11
// baseline (240.123 us; speedup 1.0000x reference)
//
#include <hip/hip_runtime.h>
#include <math.h>

#define NIMG 8
#define NCLS 80
#define HW 40000
#define M (NCLS*HW)          // 3,200,000 per image
#define UBINS 4096           // uniform bins over s in [0,1): bin = (int)(s*4096)
#define CANDL 4096           // collect cap (fallback path)
#define SPILL_CAP 65536
#define BCAP 1024
#define TOPK 1000
#define OUTK 100
#define PRE_T 0.05f
#define NMS_T 0.6f
#define FLOOR_BITS 0x3E800000u
#define FLOOR_SAFE 0.2494f

// device-global scratch; counters re-zeroed every call, rest guarded by counts
__device__ unsigned int       g_scnt[NIMG][32];    // padded: 128B per image
__device__ unsigned int       g_ovf[NIMG];
__device__ unsigned int       g_hist[NIMG][UBINS]; // 128 KB: built by k1 (R6)
__device__ unsigned short     g_xthr_b[NIMG * HW]; // bf16 thresholds (R10)
__device__ float              g_sct[NIMG * HW];    // exact sigmoid(centerness)
__device__ unsigned long long g_key[NIMG][SPILL_CAP];
// R11 phase-handoff state (k2 split into k2a/b/c/d for per-phase dur visibility)
__device__ unsigned int       g_cut[NIMG];
__device__ unsigned int       g_flag[NIMG];        // 0 ok; bit0 = k2a flag; bit1 = sort-path fail
__device__ unsigned int       g_ccnt[NIMG][32];    // padded collect counters
__device__ unsigned long long g_cand[NIMG][CANDL];
__device__ unsigned long long g_top[NIMG][TOPK];

__device__ __forceinline__ float sigmoid_exact(float x){
    return 1.0f / (1.0f + expf(-x));   // bit-matches ref (absmax 0 across sessions)
}

__device__ __forceinline__ unsigned long long shfl_xor_u64(unsigned long long v, int j){
    int lo = __shfl_xor((int)(unsigned int)(v & 0xffffffffull), j);
    int hi = __shfl_xor((int)(unsigned int)(v >> 32), j);
    return ((unsigned long long)(unsigned int)hi << 32) | (unsigned long long)(unsigned int)lo;
}

// k0: zero counters + g_hist + g_ccnt; exact sct; bf16 xthr (round toward -inf:
// spill rule stays a superset — proven R10).
__global__ void k0_init(const float* __restrict__ cent){
    int t = blockIdx.x * blockDim.x + threadIdx.x;
    if (t < NIMG * 32) ((unsigned int*)g_scnt)[t] = 0u;
    if (t < NIMG * 32) ((unsigned int*)g_ccnt)[t] = 0u;
    if (t < NIMG) g_ovf[t] = 0u;
    if (t < NIMG * UBINS) ((unsigned int*)g_hist)[t] = 0u;
    if (t < NIMG * HW){
        float pct = sigmoid_exact(cent[t]);
        g_sct[t] = pct;
        float a = FLOOR_SAFE / pct;
        float xt;
        if (a >= 1.0f) xt = 3.0e38f;
        else {
            float am = fminf(a, 0.98f);
            xt = logf(am / (1.0f - am));
        }
        unsigned xb = __float_as_uint(xt);
        unsigned hb = xb >> 16;
        if ((xb & 0x80000000u) && (xb & 0xFFFFu)) hb += 1u;
        g_xthr_b[t] = (unsigned short)hb;
    }
}

// k1: byte-identical to R10 (proven ~61 us; 3 restructures all neutral — leave it).
__global__ void __launch_bounds__(512, 8) k1_spill(const float* __restrict__ cls){
    const int n   = blockIdx.y;
    const int tid = threadIdx.x;
    const int e16 = blockIdx.x * 8192 + tid * 16;
    __shared__ unsigned long long skey[BCAP];
    __shared__ unsigned int lcnt, lbase;
    if (tid == 0) lcnt = 0u;
    __syncthreads();

    if (e16 < M){
        const int c   = e16 / HW;
        const int hw0 = e16 - c * HW;
        const float* pc = cls + (size_t)n * M + e16;
        const unsigned short* pt = g_xthr_b + n * HW + hw0;
        float4 xa[4];
        uint4  tb[2];
        #pragma unroll
        for (int i = 0; i < 4; ++i) xa[i] = *(const float4*)(pc + i * 4);
        tb[0] = *(const uint4*)(pt);
        tb[1] = *(const uint4*)(pt + 8);
        float th[16];
        #pragma unroll
        for (int q = 0; q < 2; ++q){
            unsigned w0 = (q?tb[1].x:tb[0].x), w1 = (q?tb[1].y:tb[0].y);
            unsigned w2 = (q?tb[1].z:tb[0].z), w3 = (q?tb[1].w:tb[0].w);
            th[q*8+0] = __uint_as_float((w0 & 0xFFFFu) << 16);
            th[q*8+1] = __uint_as_float((w0 >> 16) << 16);
            th[q*8+2] = __uint_as_float((w1 & 0xFFFFu) << 16);
            th[q*8+3] = __uint_as_float((w1 >> 16) << 16);
            th[q*8+4] = __uint_as_float((w2 & 0xFFFFu) << 16);
            th[q*8+5] = __uint_as_float((w2 >> 16) << 16);
            th[q*8+6] = __uint_as_float((w3 & 0xFFFFu) << 16);
            th[q*8+7] = __uint_as_float((w3 >> 16) << 16);
        }
        #define SPILL1(HWI, XV, THV) \
        if (XV >= THV){ \
            float p_ = sigmoid_exact(XV); \
            if (p_ > PRE_T){ \
                float s_ = p_ * g_sct[n * HW + (HWI)]; \
                unsigned long long key_ = ((unsigned long long)__float_as_uint(s_) << 32) \
                    | (unsigned long long)(0xFFFFFFFFu - (unsigned int)((HWI) * NCLS + c)); \
                atomicAdd(&g_hist[n][(int)(s_ * 4096.0f)], 1u); \
                unsigned int pp_ = atomicAdd(&lcnt, 1u); \
                if (pp_ < BCAP) skey[pp_] = key_; \
            } \
        }
        #pragma unroll
        for (int i = 0; i < 4; ++i){
            SPILL1(hw0 + i*4 + 0, xa[i].x, th[i*4+0])
            SPILL1(hw0 + i*4 + 1, xa[i].y, th[i*4+1])
            SPILL1(hw0 + i*4 + 2, xa[i].z, th[i*4+2])
            SPILL1(hw0 + i*4 + 3, xa[i].w, th[i*4+3])
        }
        #undef SPILL1
    }

    __syncthreads();
    unsigned int raw = lcnt;
    unsigned int cnt = raw < BCAP ? raw : BCAP;
    if (tid == 0){
        lbase = cnt ? atomicAdd(&g_scnt[n][0], cnt) : 0u;
        if (raw > BCAP) g_ovf[n] = 1u;
    }
    __syncthreads();
    unsigned int base = lbase;
    for (unsigned int i = tid; i < cnt; i += 512){
        unsigned int pos = base + i;
        if (pos < SPILL_CAP) g_key[n][pos] = skey[i];
    }
}

// ===== R11: k2 split into 4 phase kernels (per-phase dur visibility + 64-block collect)

// k2a: hist -> parallel cut-find (proven R5 logic) -> g_cut/g_flag
__global__ void __launch_bounds__(1024) k2a_cut(){
    const int n = blockIdx.x;
    const int tid = threadIdx.x;
    const int lane = tid & 63;
    const int wv   = tid >> 6;
    __shared__ unsigned int hist[UBINS];
    __shared__ unsigned int cs[256];
    __shared__ unsigned int wtot[4];
    __shared__ unsigned int s_c, s_csn, s_cut, s_Cest;

    for (int i = tid; i < UBINS; i += 1024) hist[i] = g_hist[n][i];
    if (tid == 0){ s_c = 0xFFFFFFFFu; s_csn = 0u; s_cut = 0u; s_Cest = 0u; }
    __syncthreads();

    unsigned int scnt_raw = g_scnt[n][0];
    unsigned int ovf_f    = g_ovf[n];

    if (tid < 256){
        unsigned int s = 0;
        int base = tid * 16;
        #pragma unroll
        for (int i = 0; i < 16; ++i) s += hist[base + i];
        cs[tid] = s;
    }
    __syncthreads();
    if (tid < 256){
        unsigned int v = cs[tid];
        #pragma unroll
        for (int d = 1; d < 64; d <<= 1){
            unsigned int t = __shfl_down(v, d);
            if (lane + d < 64) v += t;
        }
        if (lane == 0) wtot[wv] = v;
        cs[tid] = v;
    }
    __syncthreads();
    if (tid < 256){
        unsigned int tail = 0;
        for (int w = wv + 1; w < 4; ++w) tail += wtot[w];
        cs[tid] += tail;
    }
    __syncthreads();
    if (tid < 256){
        unsigned int a = cs[tid];
        unsigned int b = (tid == 255) ? 0u : cs[tid + 1];
        if (a >= TOPK && b < TOPK){ s_c = (unsigned int)tid; s_csn = b; }
    }
    __syncthreads();
    if (wv == 0 && s_c != 0xFFFFFFFFu){
        unsigned int cst = s_c;
        unsigned int h = (lane < 16) ? hist[cst * 16 + lane] : 0u;
        #pragma unroll
        for (int d = 1; d < 16; d <<= 1){
            unsigned int t = __shfl_down(h, d);
            if (lane + d < 16) h += t;
        }
        unsigned int gs  = h + s_csn;
        unsigned int gsn = __shfl_down(gs, 1);
        if (lane == 15) gsn = s_csn;
        if (lane < 16 && gs >= TOPK && gsn < TOPK){ s_cut = cst * 16 + lane; s_Cest = gs; }
    }
    __syncthreads();
    if (tid == 0){
        unsigned int c025 = cs[64];
        unsigned int fl = (scnt_raw > SPILL_CAP) || ovf_f || (s_c == 0xFFFFFFFFu) ||
                          (c025 < TOPK) || (s_Cest > 2048u) ? 1u : 0u;
        g_cut[n]  = s_cut;
        g_flag[n] = fl;
    }
}

// k2b: 64-block parallel collect (8 slices/image) -> g_cand via global atomic.
// Order within g_cand irrelevant (k2c sorts by unique key).
__global__ void __launch_bounds__(1024) k2b_collect(){
    const int slice = blockIdx.x;      // 0..7
    const int n     = blockIdx.y;
    const int tid   = threadIdx.x;
    const int lane  = tid & 63;
    if (g_flag[n]) return;
    unsigned int scnt_raw = g_scnt[n][0];
    unsigned int S = scnt_raw < SPILL_CAP ? scnt_raw : SPILL_CAP;
    unsigned int chunk = (S + 7) / 8;
    unsigned int lo = slice * chunk;
    unsigned int hi = lo + chunk; if (hi > S) hi = S;
    unsigned int cutb = g_cut[n];
    for (unsigned int i = lo + tid; i < hi; i += 1024){
        unsigned long long k = g_key[n][i];
        float s = __uint_as_float((unsigned int)(k >> 32));
        bool pass = ((unsigned int)(int)(s * 4096.0f)) >= cutb;
        unsigned long long mb = __ballot(pass);
        unsigned int wcnt_ = (unsigned int)__popcll(mb);
        unsigned int base = 0;
        if (lane == 0 && wcnt_) base = atomicAdd(&g_ccnt[n][0], wcnt_);
        base = (unsigned int)__builtin_amdgcn_readfirstlane((int)base);
        if (pass){
            unsigned int p = base + (unsigned int)__popcll(mb & ((1ull << lane) - 1ull));
            if (p < CANDL) g_cand[n][p] = k;
        }
    }
}

// Register/shfl bitonic steps (proven R5/R6)
#define REGSTEP(K_, J_) { \
    unsigned long long pa = shfl_xor_u64(va, (J_)); \
    unsigned long long pb = shfl_xor_u64(vb, (J_)); \
    bool fa = ((tid & (J_)) == 0); \
    bool da = ((tid & (K_)) == 0); \
    bool db = (((tid + 1024) & (K_)) == 0); \
    va = (fa == da) ? (va > pa ? va : pa) : (va < pa ? va : pa); \
    vb = (fa == db) ? (vb > pb ? vb : pb) : (vb < pb ? vb : pb); \
}
#define REGSTEP1(K_, J_) { \
    unsigned long long pa = shfl_xor_u64(va, (J_)); \
    bool fa = ((tid & (J_)) == 0); \
    bool da = ((tid & (K_)) == 0); \
    va = (fa == da) ? (va > pa ? va : pa) : (va < pa ? va : pa); \
}

// k2c: hybrid bitonic (proven R6; Nsort=1024 or 2048) on g_cand -> g_top.
// Verify-fail or C>2048 -> set flag bit1 (k2d runs full exact fallback).
__global__ void __launch_bounds__(1024) k2c_sort(){
    const int n = blockIdx.x;
    const int tid = threadIdx.x;
    __shared__ unsigned long long keysL[2048];
    __shared__ unsigned int s_srtbad;
    if (g_flag[n]) return;
    if (tid == 0) s_srtbad = 0u;
    int C = (int)g_ccnt[n][0];
    if (C > 2048){ if (tid == 0) atomicOr(&g_flag[n], 2u); return; }
    for (int i = tid; i < C; i += 1024) if (i < C) keysL[i] = g_cand[n][i];
    __syncthreads();

    if (C <= 1024){
        for (int i = C + tid; i < 1024; i += 1024) keysL[i] = 0ull;
        __syncthreads();
        unsigned long long va = keysL[tid & 1023];
        if (tid < 1024){
            REGSTEP1(2,1)
            REGSTEP1(4,2)  REGSTEP1(4,1)
            REGSTEP1(8,4)  REGSTEP1(8,2)  REGSTEP1(8,1)
            REGSTEP1(16,8) REGSTEP1(16,4) REGSTEP1(16,2) REGSTEP1(16,1)
            REGSTEP1(32,16) REGSTEP1(32,8) REGSTEP1(32,4) REGSTEP1(32,2) REGSTEP1(32,1)
            REGSTEP1(64,32) REGSTEP1(64,16) REGSTEP1(64,8) REGSTEP1(64,4) REGSTEP1(64,2) REGSTEP1(64,1)
        }
        for (int k = 128; k <= 1024; k <<= 1){
            keysL[tid] = va;
            __syncthreads();
            for (int j = k >> 1; j >= 64; j >>= 1){
                if (tid < 512){
                    int i  = ((tid & ~(j - 1)) << 1) | (tid & (j - 1));
                    int p2 = i | j;
                    unsigned long long a = keysL[i];
                    unsigned long long b = keysL[p2];
                    bool up = ((i & k) == 0);
                    if (up ? (a < b) : (a > b)){ keysL[i] = b; keysL[p2] = a; }
                }
                __syncthreads();
            }
            va = keysL[tid];
            REGSTEP1(k,32) REGSTEP1(k,16) REGSTEP1(k,8) REGSTEP1(k,4) REGSTEP1(k,2) REGSTEP1(k,1)
        }
        keysL[tid] = va;
        __syncthreads();
        if (tid <= 1022 && keysL[tid] < keysL[tid + 1]) atomicOr(&s_srtbad, 1u);
        __syncthreads();
    } else {
        for (int i = C + tid; i < 2048; i += 1024) keysL[i] = 0ull;
        __syncthreads();
        unsigned long long va = keysL[tid];
        unsigned long long vb = keysL[tid + 1024];
        REGSTEP(2,1)
        REGSTEP(4,2)  REGSTEP(4,1)
        REGSTEP(8,4)  REGSTEP(8,2)  REGSTEP(8,1)
        REGSTEP(16,8) REGSTEP(16,4) REGSTEP(16,2) REGSTEP(16,1)
        REGSTEP(32,16) REGSTEP(32,8) REGSTEP(32,4) REGSTEP(32,2) REGSTEP(32,1)
        REGSTEP(64,32) REGSTEP(64,16) REGSTEP(64,8) REGSTEP(64,4) REGSTEP(64,2) REGSTEP(64,1)
        for (int k = 128; k <= 2048; k <<= 1){
            if (k == 2048){
                unsigned long long mx = va > vb ? va : vb;
                unsigned long long mn = va > vb ? vb : va;
                va = mx; vb = mn;
            }
            keysL[tid] = va; keysL[tid + 1024] = vb;
            __syncthreads();
            for (int j = (k == 2048) ? 512 : (k >> 1); j >= 64; j >>= 1){
                int i  = ((tid & ~(j - 1)) << 1) | (tid & (j - 1));
                int p2 = i | j;
                unsigned long long a = keysL[i];
                unsigned long long b = keysL[p2];
                bool up = ((i & k) == 0);
                if (up ? (a < b) : (a > b)){ keysL[i] = b; keysL[p2] = a; }
                __syncthreads();
            }
            va = keysL[tid]; vb = keysL[tid + 1024];
            REGSTEP(k,32) REGSTEP(k,16) REGSTEP(k,8) REGSTEP(k,4) REGSTEP(k,2) REGSTEP(k,1)
        }
        keysL[tid] = va; keysL[tid + 1024] = vb;
        __syncthreads();
        bool bad = (keysL[tid] < keysL[tid + 1]);
        if (tid <= 1022) bad = bad || (keysL[tid + 1024] < keysL[tid + 1025]);
        if (bad) atomicOr(&s_srtbad, 1u);
        __syncthreads();
    }
    if (s_srtbad){ if (tid == 0) atomicOr(&g_flag[n], 2u); return; }
    if (tid < TOPK) g_top[n][tid] = keysL[tid];
}

struct SelPhase {
    unsigned int hist[UBINS];
    unsigned int cs[256];
    unsigned long long keysL[CANDL];
};
struct NmsPhase {
    float ox1[TOPK], oy1[TOPK], ox2[TOPK], oy2[TOPK], oar[TOPK];
    float bxs[TOPK][4];
    float sc[TOPK];
    int   lab[TOPK];
    int   keeplist[OUTK];
    unsigned int  Wc[16][80];
    unsigned int  ctot[80];
    unsigned int  coff[81];
    unsigned int  wcnt[16];
    unsigned short ord[1024];
    unsigned char validf[TOPK];
    unsigned char supp[TOPK];
    unsigned char keepf[1024];
};
union KU { SelPhase sel; NmsPhase nms; };

// k2d: fast path = g_top -> per-class register NMS (proven R2-R6) -> out.
// flag != 0 -> full exact fallback inline (rescan/cut/collect/sort/rank).
__global__ void __launch_bounds__(1024) k2d_nms(const float* __restrict__ cls,
                                                const float* __restrict__ loc,
                                                const float* __restrict__ reg,
                                                const int*   __restrict__ imsz,
                                                float* __restrict__ out){
    const int n = blockIdx.x;
    const int tid = threadIdx.x;
    const int lane = tid & 63;
    const int wv   = tid >> 6;
    __shared__ KU u;
    __shared__ unsigned long long stop[TOPK];
    __shared__ unsigned int lcnt, s_cut, s_nmsfb, s_cnt;

    unsigned long long kk = 0ull;
    unsigned int flag = g_flag[n];

    if (!flag){
        kk = (tid < TOPK) ? g_top[n][tid] : 0ull;
    } else {
        // ---- full exact fallback (proven machinery, ~never taken)
        for (int i = tid; i < UBINS; i += 1024) u.sel.hist[i] = 0u;
        if (tid == 0) lcnt = 0u;
        if (tid < TOPK) stop[tid] = 0ull;
        __syncthreads();
        const float* cls_n = cls + (size_t)n * M;
        const float* sct_n = g_sct + n * HW;
        for (int e = tid; e < M; e += 1024){
            float p = sigmoid_exact(cls_n[e]);
            if (p > PRE_T){
                int c = e / HW; int hw = e - c * HW;
                float s = p * sct_n[hw];
                atomicAdd(&u.sel.hist[(int)(s * 4096.0f)], 1u);
            }
        }
        __syncthreads();
        if (tid < 256){
            unsigned int s = 0;
            int base = tid * 16;
            #pragma unroll
            for (int i = 0; i < 16; ++i) s += u.sel.hist[base + i];
            u.sel.cs[tid] = s;
        }
        __syncthreads();
        if (tid == 0){
            unsigned int acc = 0; int cut = 0; int c = 255;
            for (; c >= 0; --c){ if (acc + u.sel.cs[c] >= TOPK) break; acc += u.sel.cs[c]; }
            if (c >= 0){
                int b = c*16 + 15;
                for (;; --b){ acc += u.sel.hist[b]; if (acc >= TOPK || b == c*16) break; }
                cut = b;
            }
            while (acc > CANDL && cut < UBINS){ acc -= u.sel.hist[cut]; cut++; }
            s_cut = (unsigned int)cut;
        }
        __syncthreads();
        unsigned int cutb = s_cut;
        for (int e = tid; e < M; e += 1024){
            float p = sigmoid_exact(cls_n[e]);
            if (p > PRE_T){
                int c = e / HW; int hw = e - c * HW;
                float s = p * sct_n[hw];
                if ((int)(s * 4096.0f) >= (int)cutb){
                    unsigned int pos = atomicAdd(&lcnt, 1u);
                    if (pos < CANDL){
                        unsigned int idx = (unsigned int)(hw * NCLS + c);
                        u.sel.keysL[pos] = ((unsigned long long)__float_as_uint(s) << 32)
                                         | (unsigned long long)(0xFFFFFFFFu - idx);
                    }
                }
            }
        }
        __syncthreads();
        int C = (int)(lcnt < CANDL ? lcnt : CANDL);
        if (C <= 2048){
            for (int i = C + tid; i < 2048; i += 1024) u.sel.keysL[i] = 0ull;
            __syncthreads();
            for (int k = 2; k <= 2048; k <<= 1){
                for (int j = k >> 1; j > 0; j >>= 1){
                    int i  = ((tid & ~(j - 1)) << 1) | (tid & (j - 1));
                    int p2 = i | j;
                    unsigned long long a = u.sel.keysL[i];
                    unsigned long long b = u.sel.keysL[p2];
                    bool up = ((i & k) == 0);
                    if (up ? (a < b) : (a > b)){ u.sel.keysL[i] = b; u.sel.keysL[p2] = a; }
                    __syncthreads();
                }
            }
            kk = (tid < TOPK) ? u.sel.keysL[tid] : 0ull;
        } else {
            for (int i = tid; i < C; i += 1024){
                unsigned long long k = u.sel.keysL[i];
                int rank = 0;
                for (int j = 0; j < C; ++j) rank += (u.sel.keysL[j] > k) ? 1 : 0;
                if (rank < TOPK) stop[rank] = k;
            }
            __syncthreads();
            kk = (tid < TOPK) ? stop[tid] : 0ull;
        }
    }
    __syncthreads();   // fence sel reads before union nms writes

    if (tid == 0) s_nmsfb = 0u;
    float rx1 = 0.f, ry1 = 0.f, rx2 = -1.f, ry2 = -1.f, rar = 1.f;
    float ihh = (float)imsz[2*n + 0];
    float iww = (float)imsz[2*n + 1];

    u.nms.keepf[tid] = 0;
    { unsigned int* wz = &u.nms.Wc[0][0];
      for (int i = tid; i < 16*80; i += 1024) wz[i] = 0u; }

    if (tid < TOPK){
        unsigned int bits = (unsigned int)(kk >> 32);
        float s = __uint_as_float(bits);
        u.nms.supp[tid] = 0;
        if (s > 0.0f){
            unsigned int idx = 0xFFFFFFFFu - (unsigned int)(kk & 0xFFFFFFFFull);
            int hw = (int)(idx / NCLS);
            int c  = (int)(idx % NCLS);
            int l  = c + 1;
            float x  = loc[2*hw], y = loc[2*hw + 1];
            float r0 = reg[((size_t)n*4 + 0)*HW + hw];
            float r1 = reg[((size_t)n*4 + 1)*HW + hw];
            float r2 = reg[((size_t)n*4 + 2)*HW + hw];
            float r3 = reg[((size_t)n*4 + 3)*HW + hw];
            float x1 = fminf(fmaxf(x - r0, 0.0f), iww - 1.0f);
            float y1 = fminf(fmaxf(y - r1, 0.0f), ihh - 1.0f);
            float x2 = fminf(fmaxf(x + r2, 0.0f), iww - 1.0f);
            float y2 = fminf(fmaxf(y + r3, 0.0f), ihh - 1.0f);
            u.nms.bxs[tid][0] = x1; u.nms.bxs[tid][1] = y1;
            u.nms.bxs[tid][2] = x2; u.nms.bxs[tid][3] = y2;
            float off = (float)l * 100000.0f;   // fp32, as reference (quantizes!)
            float a1 = x1 + off, b1 = y1 + off, a2 = x2 + off, b2 = y2 + off;
            float ar = (a2 - a1 + 1.0f) * (b2 - b1 + 1.0f);
            u.nms.ox1[tid] = a1; u.nms.oy1[tid] = b1;
            u.nms.ox2[tid] = a2; u.nms.oy2[tid] = b2; u.nms.oar[tid] = ar;
            rx1 = a1; ry1 = b1; rx2 = a2; ry2 = b2; rar = ar;
            u.nms.sc[tid] = s; u.nms.lab[tid] = l; u.nms.validf[tid] = 1;
        } else {
            u.nms.validf[tid] = 0; u.nms.sc[tid] = 0.0f; u.nms.lab[tid] = 0;
            u.nms.bxs[tid][0] = u.nms.bxs[tid][1] = 0.0f;
            u.nms.bxs[tid][2] = u.nms.bxs[tid][3] = 0.0f;
            u.nms.ox1[tid] = 0.f; u.nms.oy1[tid] = 0.f;
            u.nms.ox2[tid] = -1.f; u.nms.oy2[tid] = -1.f; u.nms.oar[tid] = 1.f;
        }
    }
    __syncthreads();

    // ---- class bucketing (stable in rank)
    int mk = -1;
    if (tid < TOPK && u.nms.validf[tid]) mk = u.nms.lab[tid] - 1;
    if (mk >= 0) atomicAdd(&u.nms.Wc[wv][mk], 1u);
    __syncthreads();
    if (tid < NCLS){
        unsigned int acc = 0;
        for (int w = 0; w < 16; ++w){
            unsigned int v = u.nms.Wc[w][tid];
            u.nms.Wc[w][tid] = acc;
            acc += v;
        }
        u.nms.ctot[tid] = acc;
        if (acc > 64) atomicOr(&s_nmsfb, 1u);
    }
    __syncthreads();
    if (wv == 0){
        unsigned int v = u.nms.ctot[lane];
        unsigned int inc = v;
        #pragma unroll
        for (int d = 1; d < 64; d <<= 1){
            unsigned int t = __shfl_up(inc, d);
            if (lane >= d) inc += t;
        }
        u.nms.coff[lane + 1] = inc;
        if (lane == 0) u.nms.coff[0] = 0u;
        unsigned int base = __shfl(inc, 63);
        unsigned int inc2 = (lane < 16) ? u.nms.ctot[64 + lane] : 0u;
        #pragma unroll
        for (int d = 1; d < 16; d <<= 1){
            unsigned int t = __shfl_up(inc2, d);
            if (lane >= d) inc2 += t;
        }
        if (lane < 16) u.nms.coff[65 + lane] = base + inc2;
    }
    __syncthreads();

    if (!s_nmsfb){
        int below = 0;
        for (int l = 0; l < 64; ++l){
            int ok = __shfl(mk, l);
            below += (l < lane && ok == mk) ? 1 : 0;
        }
        if (mk >= 0){
            unsigned int pos = u.nms.coff[mk] + u.nms.Wc[wv][mk] + (unsigned int)below;
            u.nms.ord[pos] = (unsigned short)tid;
        }
        __syncthreads();

        for (int k = wv; k < NCLS; k += 16){
            int base = (int)u.nms.coff[k];
            int ck   = (int)u.nms.coff[k + 1] - base;
            if (ck <= 0) continue;
            int rr = (lane < ck) ? (int)u.nms.ord[base + lane] : -1;
            float bx1 = 0.f, by1 = 0.f, bx2 = -1.f, by2 = -1.f, bar = 1.f;
            if (rr >= 0){
                bx1 = u.nms.ox1[rr]; by1 = u.nms.oy1[rr];
                bx2 = u.nms.ox2[rr]; by2 = u.nms.oy2[rr]; bar = u.nms.oar[rr];
            }
            int sup = 0;
            for (int p = 0; p < ck; ++p){
                int keep_p = !__shfl(sup, p);
                if (keep_p){
                    float px1 = __shfl(bx1, p), py1 = __shfl(by1, p);
                    float px2 = __shfl(bx2, p), py2 = __shfl(by2, p);
                    float par = __shfl(bar, p);
                    if (lane > p && rr >= 0){
                        float ix1 = fmaxf(px1, bx1);
                        float iy1 = fmaxf(py1, by1);
                        float ix2 = fminf(px2, bx2);
                        float iy2 = fminf(py2, by2);
                        float iw_ = fmaxf(ix2 - ix1 + 1.0f, 0.0f);
                        float ih_ = fmaxf(iy2 - iy1 + 1.0f, 0.0f);
                        float inter = iw_ * ih_;
                        float iou = inter / (par + bar - inter);
                        if (iou > NMS_T) sup = 1;
                    }
                }
            }
            if (rr >= 0) u.nms.keepf[rr] = sup ? 0 : 1;
        }
        __syncthreads();

        int kf = (int)u.nms.keepf[tid];
        unsigned long long mb = __ballot(kf != 0);
        if (lane == 0) u.nms.wcnt[wv] = (unsigned int)__popcll(mb);
        __syncthreads();
        if (wv == 0){
            unsigned int v = (lane < 16) ? u.nms.wcnt[lane] : 0u;
            unsigned int orig = v;
            for (int d = 1; d < 16; d <<= 1){
                unsigned int t = __shfl_up(v, d);
                if (lane >= d) v += t;
            }
            if (lane < 16) u.nms.wcnt[lane] = v - orig;
            if (lane == 15) s_cnt = (v < OUTK ? v : OUTK);
        }
        __syncthreads();
        if (kf){
            unsigned int slot = u.nms.wcnt[wv] + (unsigned int)__popcll(mb & ((1ull << lane) - 1ull));
            if (slot < OUTK) u.nms.keeplist[slot] = tid;
        }
    } else {
        int cnt = 0;
        for (int i = 0; i < TOPK; ++i){
            bool keep_i = u.nms.validf[i] && !u.nms.supp[i];
            if (keep_i){
                if (tid == 0) u.nms.keeplist[cnt] = i;
                if (tid < TOPK && tid != i){
                    float ix1 = fmaxf(u.nms.ox1[i], rx1);
                    float iy1 = fmaxf(u.nms.oy1[i], ry1);
                    float ix2 = fminf(u.nms.ox2[i], rx2);
                    float iy2 = fminf(u.nms.oy2[i], ry2);
                    float iw_ = fmaxf(ix2 - ix1 + 1.0f, 0.0f);
                    float ih_ = fmaxf(iy2 - iy1 + 1.0f, 0.0f);
                    float inter = iw_ * ih_;
                    float iou = inter / (u.nms.oar[i] + rar - inter);
                    if (iou > NMS_T) u.nms.supp[tid] = 1;
                }
                cnt++;
                __syncthreads();
                if (cnt == OUTK) break;
            }
        }
        if (tid == 0) s_cnt = (unsigned int)(cnt < OUTK ? cnt : OUTK);
    }
    __syncthreads();

    int cnt = (int)s_cnt;
    if (tid < OUTK){
        float r0=0.f,r1=0.f,r2=0.f,r3=0.f,r4=0.f,r5=0.f;
        if (tid < cnt){
            int i = u.nms.keeplist[tid];
            r0 = u.nms.bxs[i][0]; r1 = u.nms.bxs[i][1];
            r2 = u.nms.bxs[i][2]; r3 = u.nms.bxs[i][3];
            r4 = sqrtf(u.nms.sc[i]); r5 = (float)u.nms.lab[i];
        }
        float* o = out + ((size_t)n*OUTK + tid)*6;
        o[0]=r0; o[1]=r1; o[2]=r2; o[3]=r3; o[4]=r4; o[5]=r5;
    }
}

extern "C" void kernel_launch(void* const* d_in, const int* in_sizes, int n_in,
                              void* d_out, int out_size, void* d_ws, size_t ws_size,
                              hipStream_t stream){
    const float* loc  = (const float*)d_in[0];
    const float* cls  = (const float*)d_in[1];
    const float* reg  = (const float*)d_in[2];
    const float* cent = (const float*)d_in[3];
    const int*   imsz = (const int*)d_in[4];
    float* out = (float*)d_out;

    hipLaunchKernelGGL(k0_init,     dim3(625),                 dim3(512),  0, stream, cent);
    hipLaunchKernelGGL(k1_spill,    dim3((M+8191)/8192, NIMG), dim3(512),  0, stream, cls);
    hipLaunchKernelGGL(k2a_cut,     dim3(NIMG),                dim3(1024), 0, stream);
    hipLaunchKernelGGL(k2b_collect, dim3(8, NIMG),             dim3(1024), 0, stream);
    hipLaunchKernelGGL(k2c_sort,    dim3(NIMG),                dim3(1024), 0, stream);
    hipLaunchKernelGGL(k2d_nms,     dim3(NIMG),                dim3(1024), 0, stream,
                       cls, loc, reg, imsz, out);
}